// Round 7
// baseline (322.773 us; speedup 1.0000x reference)
//
#include <hip/hip_runtime.h>
#include <hip/hip_bf16.h>
#include <math.h>

typedef __hip_bfloat16 bf16;
typedef __attribute__((ext_vector_type(8))) short bf16x8;   // 8 bf16 = 4 VGPRs (MFMA A/B frag)
typedef __attribute__((ext_vector_type(4))) float floatx4;  // MFMA C/D frag

// async global->LDS, 16B per lane. LDS dest = wave-uniform base + lane*16.
__device__ __forceinline__ void async_copy16(const bf16* g, bf16* l) {
    __builtin_amdgcn_global_load_lds(
        (__attribute__((address_space(1))) void*)(void*)g,
        (__attribute__((address_space(3))) void*)(void*)l,
        16, 0, 0);
}

template <int N>
__device__ __forceinline__ void wait_vm_bar() {
    if constexpr (N == 0) asm volatile("s_waitcnt vmcnt(0)\n\ts_barrier" ::: "memory");
    else if constexpr (N == 1) asm volatile("s_waitcnt vmcnt(1)\n\ts_barrier" ::: "memory");
    else if constexpr (N == 2) asm volatile("s_waitcnt vmcnt(2)\n\ts_barrier" ::: "memory");
    else if constexpr (N == 3) asm volatile("s_waitcnt vmcnt(3)\n\ts_barrier" ::: "memory");
    else if constexpr (N == 4) asm volatile("s_waitcnt vmcnt(4)\n\ts_barrier" ::: "memory");
}

// ---------------- cast x: fp32 -> bf16, float4-vectorized ----------------
__global__ __launch_bounds__(256) void cast_f32_bf16(const float* __restrict__ in,
                                                     bf16* __restrict__ out, int n4) {
    int i = blockIdx.x * 256 + threadIdx.x;
    if (i >= n4) return;
    float4 v = ((const float4*)in)[i];
    union { ushort4 u; bf16 b[4]; } o;
    o.b[0] = __float2bfloat16(v.x);
    o.b[1] = __float2bfloat16(v.y);
    o.b[2] = __float2bfloat16(v.z);
    o.b[3] = __float2bfloat16(v.w);
    ((ushort4*)out)[i] = o.u;
}

// ------- cast + transpose: in fp32 [K][N] -> out bf16 [N][K] (LDS tile) -------
__global__ __launch_bounds__(256) void cast_transpose(const float* __restrict__ in,
                                                      bf16* __restrict__ out, int K, int N) {
    __shared__ float tile[32][33];
    int nb = blockIdx.x * 32, kb = blockIdx.y * 32;
    for (int j = threadIdx.y; j < 32; j += 8)
        tile[j][threadIdx.x] = in[(size_t)(kb + j) * N + nb + threadIdx.x];
    __syncthreads();
    for (int j = threadIdx.y; j < 32; j += 8)
        out[(size_t)(nb + j) * K + kb + threadIdx.x] = __float2bfloat16(tile[threadIdx.x][j]);
}

// ---------------- 256x256 deep-pipelined bf16 GEMM (T3+T4+T5) ----------------
// R5-proven configuration (64.7 us on QKV). BK=32, 4-deep LDS ring, counted
// vmcnt(4) boundaries. R6's per-phase barriers REGRESSED (-4%): extra barriers
// on this ledger are pure overhead — do not re-add without the full m201 port.
__global__ __launch_bounds__(512) void gemm256(const bf16* __restrict__ A,
                                               const bf16* __restrict__ Bt,
                                               bf16* __restrict__ C,
                                               int M, int N, int K) {
    __shared__ bf16 As[4][256 * 32];   // 64 KB
    __shared__ bf16 Bs[4][256 * 32];   // 64 KB
    const int tid = threadIdx.x;
    const int wave = tid >> 6, lane = tid & 63;
    const int c = lane & 15, quad = lane >> 4;
    const int wm = wave >> 2, wn = wave & 3;          // 2 x 4 wave grid
    const int mBase = blockIdx.y * 256, nBase = blockIdx.x * 256;
    const int rdOff = (quad ^ ((c >> 1) & 3)) << 3;   // swizzled read offset (elements)

    const bf16* gAs[2];
    const bf16* gBs[2];
#pragma unroll
    for (int i = 0; i < 2; i++) {
        int ci = i * 512 + tid;
        int r = ci >> 2;
        int sc = (ci & 3) ^ ((r >> 1) & 3);
        gAs[i] = A + (size_t)(mBase + r) * K + sc * 8;
        gBs[i] = Bt + (size_t)(nBase + r) * K + sc * 8;
    }
    const int ldsW = wave * 512;   // wave-uniform element offset within a half

    floatx4 acc[8][4];
#pragma unroll
    for (int mt = 0; mt < 8; mt++)
#pragma unroll
        for (int nt = 0; nt < 4; nt++) acc[mt][nt] = (floatx4){0.f, 0.f, 0.f, 0.f};

    auto stage_half = [&](int t, int i) {
        const int bb = t & 3;
        const int lo = i * 4096 + ldsW;
        async_copy16(gAs[i] + (size_t)t * 32, &As[bb][0] + lo);
        async_copy16(gBs[i] + (size_t)t * 32, &Bs[bb][0] + lo);
    };

    auto tile_body = [&](int t, bool doStage) {
        const int bb = t & 3;
        const bf16* as = &As[bb][0];
        const bf16* bs = &Bs[bb][0];
        bf16x8 bfr[4], af[4];
#pragma unroll
        for (int nt = 0; nt < 4; nt++)
            bfr[nt] = *(const bf16x8*)(bs + (wn * 64 + nt * 16 + c) * 32 + rdOff);
#pragma unroll
        for (int mt = 0; mt < 4; mt++)
            af[mt] = *(const bf16x8*)(as + (wm * 128 + mt * 16 + c) * 32 + rdOff);
        if (doStage) stage_half(t + 2, 0);
        __builtin_amdgcn_s_setprio(1);
#pragma unroll
        for (int mt = 0; mt < 4; mt++)
#pragma unroll
            for (int nt = 0; nt < 4; nt++)
                acc[mt][nt] = __builtin_amdgcn_mfma_f32_16x16x32_bf16(af[mt], bfr[nt],
                                                                      acc[mt][nt], 0, 0, 0);
        __builtin_amdgcn_s_setprio(0);
#pragma unroll
        for (int mt = 0; mt < 4; mt++)
            af[mt] = *(const bf16x8*)(as + (wm * 128 + 64 + mt * 16 + c) * 32 + rdOff);
        if (doStage) stage_half(t + 2, 1);
        __builtin_amdgcn_s_setprio(1);
#pragma unroll
        for (int mt = 0; mt < 4; mt++)
#pragma unroll
            for (int nt = 0; nt < 4; nt++)
                acc[4 + mt][nt] = __builtin_amdgcn_mfma_f32_16x16x32_bf16(af[mt], bfr[nt],
                                                                          acc[4 + mt][nt], 0, 0, 0);
        __builtin_amdgcn_s_setprio(0);
    };

    const int NT = K >> 5;   // K-tiles of 32
    stage_half(0, 0); stage_half(0, 1);
    stage_half(1, 0); stage_half(1, 1);
    asm volatile("s_waitcnt vmcnt(4)\n\ts_barrier" ::: "memory");

    for (int t = 0; t < NT - 2; ++t) {
        tile_body(t, true);
        asm volatile("s_waitcnt vmcnt(4)\n\ts_barrier" ::: "memory");
    }
    tile_body(NT - 2, false);
    asm volatile("s_waitcnt vmcnt(0)\n\ts_barrier" ::: "memory");   // epilogue drain
    tile_body(NT - 1, false);

#pragma unroll
    for (int mt = 0; mt < 8; mt++)
#pragma unroll
        for (int nt = 0; nt < 4; nt++)
#pragma unroll
            for (int r = 0; r < 4; r++) {
                int row = mBase + wm * 128 + mt * 16 + quad * 4 + r;
                int col = nBase + wn * 64 + nt * 16 + c;
                C[(size_t)row * N + col] = __float2bfloat16(acc[mt][nt][r]);
            }
}

// ------- generic deep-pipelined GEMM (T1+T3+T4+T5), 8 waves (2M x 4N) -------
// Used for out-proj (BM=128, BN=256), R5-proven configuration.
template <int BM, int BN, bool OUTF32>
__global__ __launch_bounds__(512) void gemm256g(const bf16* __restrict__ A,
                                                const bf16* __restrict__ Bt,
                                                void* __restrict__ Cout,
                                                int M, int N, int K) {
    constexpr int CA = BM * 4;              // 16B chunks per A k-tile
    constexpr int CB = BN * 4;
    constexpr int A_LPT = CA / 512;         // uniform A loads per thread (1 or 2)
    constexpr int EXTRA = CB - 512;         // threads issuing a 2nd B load
    constexpr int WM = BM / 2, WN = BN / 4; // per-wave output tile
    constexpr int MT = WM / 16, NT = WN / 16;
    __shared__ bf16 As[4][BM * 32];
    __shared__ bf16 Bs[4][BN * 32];
    const int tid = threadIdx.x;
    const int wave = tid >> 6, lane = tid & 63;
    const int c = lane & 15, quad = lane >> 4;
    const int wm = wave >> 2, wn = wave & 3;

    // XCD-aware swizzle (bijective: grid total divisible by 8)
    const int GX = gridDim.x;
    const int GB = GX * gridDim.y;
    int bid = blockIdx.y * GX + blockIdx.x;
    bid = (bid & 7) * (GB >> 3) + (bid >> 3);
    const int mBase = (bid / GX) * BM, nBase = (bid % GX) * BN;

    const int rdOff = (quad ^ ((c >> 1) & 3)) << 3;   // swizzled read offset (elems)
    const bool heavy = (EXTRA == 512) ? true : (tid < EXTRA);   // wave-uniform

    const bf16* gA[A_LPT];
#pragma unroll
    for (int s = 0; s < A_LPT; s++) {
        int ci = s * 512 + tid;
        int r = ci >> 2;
        int sc = (ci & 3) ^ ((r >> 1) & 3);
        gA[s] = A + (size_t)(mBase + r) * K + sc * 8;
    }
    const bf16* gB0;
    {
        int r = tid >> 2;
        int sc = (tid & 3) ^ ((r >> 1) & 3);
        gB0 = Bt + (size_t)(nBase + r) * K + sc * 8;
    }
    const bf16* gB1 = nullptr;
    if (heavy) {
        int ci = 512 + tid;
        int r = ci >> 2;
        int sc = (ci & 3) ^ ((r >> 1) & 3);
        gB1 = Bt + (size_t)(nBase + r) * K + sc * 8;
    }

    floatx4 acc[MT][NT];
#pragma unroll
    for (int mt = 0; mt < MT; mt++)
#pragma unroll
        for (int nt = 0; nt < NT; nt++) acc[mt][nt] = (floatx4){0.f, 0.f, 0.f, 0.f};

    auto stage_a = [&](int t) {
        const int bb = t & 3;
#pragma unroll
        for (int s = 0; s < A_LPT; s++)
            async_copy16(gA[s] + (size_t)t * 32, &As[bb][(s * 512 + tid) * 8]);
    };
    auto stage_b = [&](int t) {
        const int bb = t & 3;
        async_copy16(gB0 + (size_t)t * 32, &Bs[bb][tid * 8]);
        if (heavy) async_copy16(gB1 + (size_t)t * 32, &Bs[bb][(512 + tid) * 8]);
    };
    auto boundary = [&]() {   // counted: tile t+1 landed, t+2's own loads in flight
        if (heavy) wait_vm_bar<A_LPT + 2>();
        else       wait_vm_bar<A_LPT + 1>();
    };

    auto tile_body = [&](int t, bool doStage) {
        const int bb = t & 3;
        const bf16* as = &As[bb][0];
        const bf16* bs = &Bs[bb][0];
        bf16x8 bfr[NT], af[MT / 2];
#pragma unroll
        for (int nt = 0; nt < NT; nt++)
            bfr[nt] = *(const bf16x8*)(bs + (wn * WN + nt * 16 + c) * 32 + rdOff);
#pragma unroll
        for (int mt = 0; mt < MT / 2; mt++)
            af[mt] = *(const bf16x8*)(as + (wm * WM + mt * 16 + c) * 32 + rdOff);
        if (doStage) stage_a(t + 2);
        __builtin_amdgcn_s_setprio(1);
#pragma unroll
        for (int mt = 0; mt < MT / 2; mt++)
#pragma unroll
            for (int nt = 0; nt < NT; nt++)
                acc[mt][nt] = __builtin_amdgcn_mfma_f32_16x16x32_bf16(af[mt], bfr[nt],
                                                                      acc[mt][nt], 0, 0, 0);
        __builtin_amdgcn_s_setprio(0);
#pragma unroll
        for (int mt = 0; mt < MT / 2; mt++)
            af[mt] = *(const bf16x8*)(as + (wm * WM + (MT / 2 + mt) * 16 + c) * 32 + rdOff);
        if (doStage) stage_b(t + 2);
        __builtin_amdgcn_s_setprio(1);
#pragma unroll
        for (int mt = 0; mt < MT / 2; mt++)
#pragma unroll
            for (int nt = 0; nt < NT; nt++)
                acc[MT / 2 + mt][nt] = __builtin_amdgcn_mfma_f32_16x16x32_bf16(
                    af[mt], bfr[nt], acc[MT / 2 + mt][nt], 0, 0, 0);
        __builtin_amdgcn_s_setprio(0);
    };

    const int NTK = K >> 5;   // K-tiles of 32
    stage_a(0); stage_b(0);
    stage_a(1); stage_b(1);
    boundary();

    for (int t = 0; t < NTK - 2; ++t) {
        tile_body(t, true);
        boundary();
    }
    tile_body(NTK - 2, false);
    wait_vm_bar<0>();   // epilogue drain
    tile_body(NTK - 1, false);

#pragma unroll
    for (int mt = 0; mt < MT; mt++)
#pragma unroll
        for (int nt = 0; nt < NT; nt++)
#pragma unroll
            for (int r = 0; r < 4; r++) {
                int row = mBase + wm * WM + mt * 16 + quad * 4 + r;
                int col = nBase + wn * WN + nt * 16 + c;
                if (OUTF32)
                    ((float*)Cout)[(size_t)row * N + col] = acc[mt][nt][r];
                else
                    ((bf16*)Cout)[(size_t)row * N + col] = __float2bfloat16(acc[mt][nt][r]);
            }
}

// ---------------- RoPE (K only), in place on bf16 ----------------
__global__ __launch_bounds__(256) void rope_kernel(bf16* __restrict__ X, int heads, int rowStride) {
    int idx = blockIdx.x * 256 + threadIdx.x;
    int d = idx & 63;
    int h = (idx >> 6) % heads;
    int row = idx / (heads * 64);
    int t = row & 2047;
    float theta = exp2f(-(float)d * 0.20762050593045827f);  // 10000^(-d/64)
    float ang = (float)t * theta;
    float sv, cv;
    __sincosf(ang, &sv, &cv);
    bf16* p = X + (size_t)row * rowStride + h * 128 + d;
    float x1 = __bfloat162float(p[0]);
    float x2 = __bfloat162float(p[64]);
    p[0]  = __float2bfloat16(x1 * cv - x2 * sv);
    p[64] = __float2bfloat16(x2 * cv + x1 * sv);
}

// ------- V transpose: QKV V-block [t][d] -> Vtg [b*4+kvh][d=128][t=2048] -------
// Keys are sigma-permuted within each 32-key chunk so that the flash kernel's
// in-register P fragment (from swapped QK^T) lines up with V's MFMA k-slots:
// Vtg position p holds key sigma(p), sigma(quad*8+j) = (j>=4?16:0)+quad*4+(j&3).
// Writing: key k lands at position sigma^{-1}(k) = ((g&3)*2 + g>>2)*4 + (k&3), g=k>>2.
__global__ __launch_bounds__(256) void vtrans(const bf16* __restrict__ QKV,
                                              bf16* __restrict__ Vtg) {
    __shared__ bf16 tile[32][34];
    const int bh = blockIdx.z;
    const int b = bh >> 2, kvh = bh & 3;
    const int t0 = blockIdx.x * 32, d0 = blockIdx.y * 32;
    const bf16* src = QKV + (size_t)b * 2048 * 3072 + 2560 + kvh * 128;
    const int tx = threadIdx.x;
    for (int j = threadIdx.y; j < 32; j += 8)
        tile[j][tx] = src[(size_t)(t0 + j) * 3072 + d0 + tx];
    __syncthreads();
    bf16* dst = Vtg + (size_t)bh * 128 * 2048;
    const int g = tx >> 2;
    const int txp = (((g & 3) << 1) | (g >> 2)) * 4 + (tx & 3);   // sigma^{-1}(tx)
    for (int j = threadIdx.y; j < 32; j += 8)
        dst[(size_t)(d0 + j) * 2048 + t0 + txp] = tile[tx][j];
}

// ---------------- flash attention v7: swapped QK^T + double-buffered K/V ----------------
// R7: T3-minimal 2-phase pipeline. Per kv-tile: issue STAGE(t+1, buf^1) BEFORE
// computing tile t, then one vmcnt(0)+s_barrier per tile. K/V fetch latency
// (L2-warm, panel reused by 128 blocks) hides under the 32-MFMA+softmax compute.
// LDS 64 KB -> 2 blocks/CU (was 4): pipeline self-hides instead of TLP.
// Ring safety: buf is overwritten one full barrier after its last reader; per-wave
// vmcnt(0) before the shared barrier covers all waves' loads.
__global__ __launch_bounds__(256, 2) void flash_attn7(const bf16* __restrict__ QKV,
                                                      const bf16* __restrict__ Vtg,
                                                      bf16* __restrict__ Slot0,
                                                      bf16* __restrict__ Slot1,
                                                      float* __restrict__ Ls) {
    const int T = 2048, STR = 3072;
    __shared__ bf16 Ks[2][4 * 64 * 32];   // 32 KB  [buf][d-chunk][key 64][32]
    __shared__ bf16 Vs[2][2 * 128 * 32];  // 32 KB  [buf][key-chunk][d 128][32]
    const int b = blockIdx.z, h = blockIdx.y;
    const int pj = blockIdx.x >> 1, s = blockIdx.x & 1;
    const int kvh = h >> 2;
    const int tid = threadIdx.x, wave = tid >> 6, lane = tid & 63;
    const int c = lane & 15, quad = lane >> 4;
    const float C2 = 0.12751541717525597f;  // (1/sqrt(128)) * log2(e), folded into Q

    const bf16* Kg = QKV + (size_t)b * T * STR + 2048 + kvh * 128;
    const bf16* Vg = Vtg + (size_t)(b * 4 + kvh) * 128 * 2048;
    const int srow = tid >> 2;
    const int xcol = ((tid & 3) ^ ((tid >> 3) & 3)) << 3;   // swizzled staging chunk
    const int koff = (quad ^ ((c >> 1) & 3)) << 3;          // swizzled read offset
    const int qa = 31 - pj;

    auto stage = [&](int buf, int kt) {
        const int kt0 = kt * 64;
#pragma unroll
        for (int it = 0; it < 4; it++) {
            async_copy16(Kg + (size_t)(kt0 + srow) * STR + it * 32 + xcol,
                         &Ks[buf][0] + it * 2048 + wave * 512);
            async_copy16(Vg + (size_t)((it & 1) * 64 + srow) * 2048 + kt0 + (it >> 1) * 32 + xcol,
                         &Vs[buf][0] + it * 2048 + wave * 512);
        }
    };

    auto run_part = [&](int qtile, int ktlo, int kthi, bf16* slot, int lsSlot) {
        const int q0 = qtile * 64;
        // prologue stage for first tile (valid memory even for empty ranges)
        stage(0, ktlo < 32 ? ktlo : 31);
        // Q frags + RoPE + scale fold, in-register (overlaps first-tile staging)
        bf16x8 qf[4];
        {
            const bf16* qp = QKV + ((size_t)b * T + q0 + wave * 16 + c) * STR + h * 128 + quad * 8;
#pragma unroll
            for (int ks = 0; ks < 4; ks++) qf[ks] = *(const bf16x8*)(qp + ks * 32);
            const float t = (float)(q0 + wave * 16 + c);
#pragma unroll
            for (int ks = 0; ks < 2; ks++)
#pragma unroll
                for (int j = 0; j < 8; j++) {
                    int d = ks * 32 + quad * 8 + j;
                    float theta = exp2f((float)d * -0.20762050593045827f);
                    float sv, cv;
                    __sincosf(t * theta, &sv, &cv);
                    float lo = __bfloat162float(((const bf16*)&qf[ks])[j]);
                    float hi = __bfloat162float(((const bf16*)&qf[ks + 2])[j]);
                    ((bf16*)&qf[ks])[j]     = __float2bfloat16((lo * cv - hi * sv) * C2);
                    ((bf16*)&qf[ks + 2])[j] = __float2bfloat16((hi * cv + lo * sv) * C2);
                }
        }
        floatx4 accO[8];
#pragma unroll
        for (int nt = 0; nt < 8; nt++) accO[nt] = (floatx4){0.f, 0.f, 0.f, 0.f};
        float lsum = 0.f;

        asm volatile("s_waitcnt vmcnt(0)\n\ts_barrier" ::: "memory");
        int cur = 0;
        for (int kt = ktlo; kt < kthi; kt++) {
            if (kt + 1 < kthi) stage(cur ^ 1, kt + 1);   // prefetch next tile
            const bf16* ks_ = &Ks[cur][0];
            const bf16* vs_ = &Vs[cur][0];
            // swapped QK^T: sf[nt] = S^T[key nt*16+quad*4+r][q = c]
            floatx4 sf[4];
#pragma unroll
            for (int nt = 0; nt < 4; nt++) sf[nt] = (floatx4){0.f, 0.f, 0.f, 0.f};
#pragma unroll
            for (int ks = 0; ks < 4; ks++)
#pragma unroll
                for (int nt = 0; nt < 4; nt++) {
                    bf16x8 kf = *(const bf16x8*)(ks_ + ks * 2048 + (nt * 16 + c) * 32 + koff);
                    sf[nt] = __builtin_amdgcn_mfma_f32_16x16x32_bf16(kf, qf[ks], sf[nt], 0, 0, 0);
                }
            // softmax numerator, fully in-register (lane c owns q-row q0+wave*16+c)
            if (kt == qtile) {
                const int qrel = wave * 16 + c;
#pragma unroll
                for (int nt = 0; nt < 4; nt++)
#pragma unroll
                    for (int r = 0; r < 4; r++) {
                        float p = exp2f(sf[nt][r]);
                        if (nt * 16 + quad * 4 + r > qrel) p = 0.f;
                        lsum += p;
                        sf[nt][r] = p;
                    }
            } else {
#pragma unroll
                for (int nt = 0; nt < 4; nt++)
#pragma unroll
                    for (int r = 0; r < 4; r++) {
                        float p = exp2f(sf[nt][r]);
                        lsum += p;
                        sf[nt][r] = p;
                    }
            }
            // PV: pack P in-register; V key-slots sigma-matched by vtrans
#pragma unroll
            for (int kc = 0; kc < 2; kc++) {
                bf16x8 pf;
#pragma unroll
                for (int j = 0; j < 4; j++) {
                    ((bf16*)&pf)[j]     = __float2bfloat16(sf[2 * kc][j]);
                    ((bf16*)&pf)[4 + j] = __float2bfloat16(sf[2 * kc + 1][j]);
                }
#pragma unroll
                for (int nt = 0; nt < 8; nt++) {
                    bf16x8 vf = *(const bf16x8*)(vs_ + kc * 4096 + (nt * 16 + c) * 32 + koff);
                    accO[nt] = __builtin_amdgcn_mfma_f32_16x16x32_bf16(pf, vf, accO[nt], 0, 0, 0);
                }
            }
            // next tile's loads landed (mostly under compute); all waves aligned
            asm volatile("s_waitcnt vmcnt(0)\n\ts_barrier" ::: "memory");
            cur ^= 1;
        }
        // row-sum: reduce over the 4 quads holding this q-row's keys
        {
            float v = lsum;
            v += __shfl_xor(v, 16);
            v += __shfl_xor(v, 32);
            if (quad == 0)
                Ls[(size_t)lsSlot * 65536 + ((size_t)(b * 16 + h) * 32 + qtile) * 64
                   + wave * 16 + c] = v;
        }
        const size_t orow = (size_t)b * T + q0 + wave * 16 + quad * 4;
#pragma unroll
        for (int nt = 0; nt < 8; nt++)
#pragma unroll
            for (int r = 0; r < 4; r++)
                slot[(orow + r) * 2048 + h * 128 + nt * 16 + c] =
                    __float2bfloat16(accO[nt][r]);
    };

    if (s == 0) {
        run_part(qa, 0, 17, Slot0, 0);
    } else {
        run_part(qa, 17, 32 - pj, Slot1, 1);   // empty for pj==15 -> writes zeros
        run_part(pj, 0, pj + 1, Slot0, 0);
    }
}

// ---------------- merge partials: AO = (Slot0 + Slot1) / (l0 + l1) ----------------
__global__ __launch_bounds__(256) void attn_merge(bf16* __restrict__ AO,
                                                  const bf16* __restrict__ P1,
                                                  const float* __restrict__ Ls) {
    int i = blockIdx.x * 256 + threadIdx.x;   // 1,048,576 threads, 8 cols each
    int row = i >> 8;                         // 0..4095
    int cg = (i & 255) << 3;                  // col 0..2040 step 8
    int b = row >> 11, t = row & 2047;
    int qtile = t >> 6;
    int h = cg >> 7;
    size_t off = (size_t)row * 2048 + cg;
    size_t li = ((size_t)(b * 16 + h) * 32 + qtile) * 64 + (t & 63);
    bf16x8 a0 = *(const bf16x8*)(AO + off);
    float l = Ls[li];
    float acc[8];
#pragma unroll
    for (int j = 0; j < 8; j++) acc[j] = __bfloat162float(((const bf16*)&a0)[j]);
    if (qtile >= 16) {   // q-tiles 16..31 have a second partial
        bf16x8 a1 = *(const bf16x8*)(P1 + off);
        l += Ls[65536 + li];
#pragma unroll
        for (int j = 0; j < 8; j++) acc[j] += __bfloat162float(((const bf16*)&a1)[j]);
    }
    float inv = 1.0f / l;
    bf16x8 o;
#pragma unroll
    for (int j = 0; j < 8; j++) ((bf16*)&o)[j] = __float2bfloat16(acc[j] * inv);
    *(bf16x8*)(AO + off) = o;
}

extern "C" void kernel_launch(void* const* d_in, const int* in_sizes, int n_in,
                              void* d_out, int out_size, void* d_ws, size_t ws_size,
                              hipStream_t stream) {
    const float* x  = (const float*)d_in[0];
    const float* Wq = (const float*)d_in[1];
    const float* Wk = (const float*)d_in[2];
    const float* Wv = (const float*)d_in[3];
    const float* Wo = (const float*)d_in[4];

    char* ws = (char*)d_ws;
    bf16* xb   = (bf16*)(ws);                 // [4096][2048] (dead after QKV GEMM)
    bf16* Vtg  = (bf16*)(ws);                 // reuses xb: [8][128][2048] = 4 MB
    bf16* Slt1 = (bf16*)(ws + 4194304);       // 16.78 MB, overlays dead xb-tail + Wt
    float* Ls  = (float*)(ws + 20971520);     // 0.5 MB lsum[2][b][h][qtile][64]
    bf16* Wt   = (bf16*)(ws + 16777216);      // [3072][2048] Wq|Wk|Wv (dead before flash)
    bf16* Wot  = (bf16*)(ws + 29360128);      // [2048][2048] (live until out-proj)
    bf16* QKV  = (bf16*)(ws + 37748736);      // [4096][3072]
    bf16* AO   = (bf16*)(ws + 62914560);      // [4096][2048] = partial Slot0, merged in place

    cast_f32_bf16<<<8192, 256, 0, stream>>>(x, xb, 2097152);
    cast_transpose<<<dim3(64, 64), dim3(32, 8), 0, stream>>>(Wq, Wt, 2048, 2048);
    cast_transpose<<<dim3(16, 64), dim3(32, 8), 0, stream>>>(Wk, Wt + 2048 * 2048, 2048, 512);
    cast_transpose<<<dim3(16, 64), dim3(32, 8), 0, stream>>>(Wv, Wt + 2560 * 2048, 2048, 512);
    cast_transpose<<<dim3(64, 64), dim3(32, 8), 0, stream>>>(Wo, Wot, 2048, 2048);

    // QKV projection: proven 256^2 kernel (R5: 64.7 us), grid 12x16 = 192 blocks
    gemm256<<<dim3(12, 16), 512, 0, stream>>>(xb, Wt, QKV, 4096, 3072, 2048);

    // RoPE on K only (Q-RoPE fused into flash_attn7)
    rope_kernel<<<4096, 256, 0, stream>>>(QKV + 2048, 4, 3072);

    // V transpose (into Vtg at ws base), sigma-permuted keys within 32-chunks
    vtrans<<<dim3(64, 4, 8), dim3(32, 8), 0, stream>>>(QKV, Vtg);

    // split-kv flash attention: 16 pairs x 2 splits x 16 heads x 2 batch = 1024 uniform blocks
    flash_attn7<<<dim3(32, 16, 2), 256, 0, stream>>>(QKV, Vtg, AO, Slt1, Ls);

    // merge partials -> AO (in place)
    attn_merge<<<4096, 256, 0, stream>>>(AO, Slt1, Ls);

    // output projection: 128x256 tiles -> grid 8x32 = 256 blocks (full CU coverage)
    gemm256g<128, 256, true><<<dim3(8, 32), 512, 0, stream>>>(AO, Wot, d_out, 4096, 2048, 2048);
}

// Round 8
// 305.664 us; speedup vs baseline: 1.0560x; 1.0560x over previous
//
#include <hip/hip_runtime.h>
#include <hip/hip_bf16.h>
#include <math.h>

typedef __hip_bfloat16 bf16;
typedef __attribute__((ext_vector_type(8))) short bf16x8;   // 8 bf16 = 4 VGPRs (MFMA A/B frag)
typedef __attribute__((ext_vector_type(4))) float floatx4;  // MFMA C/D frag

// async global->LDS, 16B per lane. LDS dest = wave-uniform base + lane*16.
__device__ __forceinline__ void async_copy16(const bf16* g, bf16* l) {
    __builtin_amdgcn_global_load_lds(
        (__attribute__((address_space(1))) void*)(void*)g,
        (__attribute__((address_space(3))) void*)(void*)l,
        16, 0, 0);
}

template <int N>
__device__ __forceinline__ void wait_vm_bar() {
    if constexpr (N == 0) asm volatile("s_waitcnt vmcnt(0)\n\ts_barrier" ::: "memory");
    else if constexpr (N == 1) asm volatile("s_waitcnt vmcnt(1)\n\ts_barrier" ::: "memory");
    else if constexpr (N == 2) asm volatile("s_waitcnt vmcnt(2)\n\ts_barrier" ::: "memory");
    else if constexpr (N == 3) asm volatile("s_waitcnt vmcnt(3)\n\ts_barrier" ::: "memory");
    else if constexpr (N == 4) asm volatile("s_waitcnt vmcnt(4)\n\ts_barrier" ::: "memory");
    else if constexpr (N == 5) asm volatile("s_waitcnt vmcnt(5)\n\ts_barrier" ::: "memory");
    else if constexpr (N == 6) asm volatile("s_waitcnt vmcnt(6)\n\ts_barrier" ::: "memory");
    else if constexpr (N == 7) asm volatile("s_waitcnt vmcnt(7)\n\ts_barrier" ::: "memory");
    else if constexpr (N == 8) asm volatile("s_waitcnt vmcnt(8)\n\ts_barrier" ::: "memory");
}

// ---------------- cast x: fp32 -> bf16, float4-vectorized ----------------
__global__ __launch_bounds__(256) void cast_f32_bf16(const float* __restrict__ in,
                                                     bf16* __restrict__ out, int n4) {
    int i = blockIdx.x * 256 + threadIdx.x;
    if (i >= n4) return;
    float4 v = ((const float4*)in)[i];
    union { ushort4 u; bf16 b[4]; } o;
    o.b[0] = __float2bfloat16(v.x);
    o.b[1] = __float2bfloat16(v.y);
    o.b[2] = __float2bfloat16(v.z);
    o.b[3] = __float2bfloat16(v.w);
    ((ushort4*)out)[i] = o.u;
}

// ------- cast + transpose: in fp32 [K][N] -> out bf16 [N][K] (LDS tile) -------
__global__ __launch_bounds__(256) void cast_transpose(const float* __restrict__ in,
                                                      bf16* __restrict__ out, int K, int N) {
    __shared__ float tile[32][33];
    int nb = blockIdx.x * 32, kb = blockIdx.y * 32;
    for (int j = threadIdx.y; j < 32; j += 8)
        tile[j][threadIdx.x] = in[(size_t)(kb + j) * N + nb + threadIdx.x];
    __syncthreads();
    for (int j = threadIdx.y; j < 32; j += 8)
        out[(size_t)(nb + j) * K + kb + threadIdx.x] = __float2bfloat16(tile[threadIdx.x][j]);
}

// ---------------- 256x256 deep-pipelined bf16 GEMM (T3+T4+T5) ----------------
// R8: prefetch distance 2 -> 3 on the proven R5 structure. Stage t+3 during tile t
// (in-flight ~2 tile-bodies, covering HBM-miss latency ~900cy), boundary vmcnt(8).
// Ring: buf (t+3)&3 = (t-1)&3 whose readers finished before the previous barrier.
// R6's per-phase barriers REGRESSED — do not re-add.
__global__ __launch_bounds__(512) void gemm256(const bf16* __restrict__ A,
                                               const bf16* __restrict__ Bt,
                                               bf16* __restrict__ C,
                                               int M, int N, int K) {
    __shared__ bf16 As[4][256 * 32];   // 64 KB
    __shared__ bf16 Bs[4][256 * 32];   // 64 KB
    const int tid = threadIdx.x;
    const int wave = tid >> 6, lane = tid & 63;
    const int c = lane & 15, quad = lane >> 4;
    const int wm = wave >> 2, wn = wave & 3;          // 2 x 4 wave grid
    const int mBase = blockIdx.y * 256, nBase = blockIdx.x * 256;
    const int rdOff = (quad ^ ((c >> 1) & 3)) << 3;   // swizzled read offset (elements)

    const bf16* gAs[2];
    const bf16* gBs[2];
#pragma unroll
    for (int i = 0; i < 2; i++) {
        int ci = i * 512 + tid;
        int r = ci >> 2;
        int sc = (ci & 3) ^ ((r >> 1) & 3);
        gAs[i] = A + (size_t)(mBase + r) * K + sc * 8;
        gBs[i] = Bt + (size_t)(nBase + r) * K + sc * 8;
    }
    const int ldsW = wave * 512;   // wave-uniform element offset within a half

    floatx4 acc[8][4];
#pragma unroll
    for (int mt = 0; mt < 8; mt++)
#pragma unroll
        for (int nt = 0; nt < 4; nt++) acc[mt][nt] = (floatx4){0.f, 0.f, 0.f, 0.f};

    auto stage_half = [&](int t, int i) {
        const int bb = t & 3;
        const int lo = i * 4096 + ldsW;
        async_copy16(gAs[i] + (size_t)t * 32, &As[bb][0] + lo);
        async_copy16(gBs[i] + (size_t)t * 32, &Bs[bb][0] + lo);
    };

    auto tile_body = [&](int t, bool doStage) {
        const int bb = t & 3;
        const bf16* as = &As[bb][0];
        const bf16* bs = &Bs[bb][0];
        bf16x8 bfr[4], af[4];
#pragma unroll
        for (int nt = 0; nt < 4; nt++)
            bfr[nt] = *(const bf16x8*)(bs + (wn * 64 + nt * 16 + c) * 32 + rdOff);
#pragma unroll
        for (int mt = 0; mt < 4; mt++)
            af[mt] = *(const bf16x8*)(as + (wm * 128 + mt * 16 + c) * 32 + rdOff);
        if (doStage) stage_half(t + 3, 0);
        __builtin_amdgcn_s_setprio(1);
#pragma unroll
        for (int mt = 0; mt < 4; mt++)
#pragma unroll
            for (int nt = 0; nt < 4; nt++)
                acc[mt][nt] = __builtin_amdgcn_mfma_f32_16x16x32_bf16(af[mt], bfr[nt],
                                                                      acc[mt][nt], 0, 0, 0);
        __builtin_amdgcn_s_setprio(0);
#pragma unroll
        for (int mt = 0; mt < 4; mt++)
            af[mt] = *(const bf16x8*)(as + (wm * 128 + 64 + mt * 16 + c) * 32 + rdOff);
        if (doStage) stage_half(t + 3, 1);
        __builtin_amdgcn_s_setprio(1);
#pragma unroll
        for (int mt = 0; mt < 4; mt++)
#pragma unroll
            for (int nt = 0; nt < 4; nt++)
                acc[4 + mt][nt] = __builtin_amdgcn_mfma_f32_16x16x32_bf16(af[mt], bfr[nt],
                                                                          acc[4 + mt][nt], 0, 0, 0);
        __builtin_amdgcn_s_setprio(0);
    };

    const int NT = K >> 5;   // K-tiles of 32 (NT >= 4)
    stage_half(0, 0); stage_half(0, 1);
    stage_half(1, 0); stage_half(1, 1);
    stage_half(2, 0); stage_half(2, 1);
    wait_vm_bar<8>();   // t0 landed; t1,t2 in flight

    for (int t = 0; t < NT - 3; ++t) {
        tile_body(t, true);          // stages t+3
        wait_vm_bar<8>();            // t+1 landed; t+2,t+3 in flight
    }
    tile_body(NT - 3, false);
    wait_vm_bar<4>();                // NT-2 landed; NT-1 in flight
    tile_body(NT - 2, false);
    wait_vm_bar<0>();                // NT-1 landed
    tile_body(NT - 1, false);

#pragma unroll
    for (int mt = 0; mt < 8; mt++)
#pragma unroll
        for (int nt = 0; nt < 4; nt++)
#pragma unroll
            for (int r = 0; r < 4; r++) {
                int row = mBase + wm * 128 + mt * 16 + quad * 4 + r;
                int col = nBase + wn * 64 + nt * 16 + c;
                C[(size_t)row * N + col] = __float2bfloat16(acc[mt][nt][r]);
            }
}

// ------- generic deep-pipelined GEMM (T1+T3+T4+T5), 8 waves (2M x 4N) -------
// Used for out-proj (BM=128, BN=256). R8: prefetch depth 3 (same ledger concept).
template <int BM, int BN, bool OUTF32>
__global__ __launch_bounds__(512) void gemm256g(const bf16* __restrict__ A,
                                                const bf16* __restrict__ Bt,
                                                void* __restrict__ Cout,
                                                int M, int N, int K) {
    constexpr int CA = BM * 4;              // 16B chunks per A k-tile
    constexpr int CB = BN * 4;
    constexpr int A_LPT = CA / 512;         // uniform A loads per thread (1 or 2)
    constexpr int EXTRA = CB - 512;         // threads issuing a 2nd B load
    constexpr int WM = BM / 2, WN = BN / 4; // per-wave output tile
    constexpr int MT = WM / 16, NT = WN / 16;
    constexpr int LH = A_LPT + 2;           // loads/thread/tile, heavy waves
    constexpr int LL = A_LPT + 1;           // loads/thread/tile, light waves
    __shared__ bf16 As[4][BM * 32];
    __shared__ bf16 Bs[4][BN * 32];
    const int tid = threadIdx.x;
    const int wave = tid >> 6, lane = tid & 63;
    const int c = lane & 15, quad = lane >> 4;
    const int wm = wave >> 2, wn = wave & 3;

    // XCD-aware swizzle (bijective: grid total divisible by 8)
    const int GX = gridDim.x;
    const int GB = GX * gridDim.y;
    int bid = blockIdx.y * GX + blockIdx.x;
    bid = (bid & 7) * (GB >> 3) + (bid >> 3);
    const int mBase = (bid / GX) * BM, nBase = (bid % GX) * BN;

    const int rdOff = (quad ^ ((c >> 1) & 3)) << 3;   // swizzled read offset (elems)
    const bool heavy = (EXTRA == 512) ? true : (tid < EXTRA);   // wave-uniform

    const bf16* gA[A_LPT];
#pragma unroll
    for (int s = 0; s < A_LPT; s++) {
        int ci = s * 512 + tid;
        int r = ci >> 2;
        int sc = (ci & 3) ^ ((r >> 1) & 3);
        gA[s] = A + (size_t)(mBase + r) * K + sc * 8;
    }
    const bf16* gB0;
    {
        int r = tid >> 2;
        int sc = (tid & 3) ^ ((r >> 1) & 3);
        gB0 = Bt + (size_t)(nBase + r) * K + sc * 8;
    }
    const bf16* gB1 = nullptr;
    if (heavy) {
        int ci = 512 + tid;
        int r = ci >> 2;
        int sc = (ci & 3) ^ ((r >> 1) & 3);
        gB1 = Bt + (size_t)(nBase + r) * K + sc * 8;
    }

    floatx4 acc[MT][NT];
#pragma unroll
    for (int mt = 0; mt < MT; mt++)
#pragma unroll
        for (int nt = 0; nt < NT; nt++) acc[mt][nt] = (floatx4){0.f, 0.f, 0.f, 0.f};

    auto stage_a = [&](int t) {
        const int bb = t & 3;
#pragma unroll
        for (int s = 0; s < A_LPT; s++)
            async_copy16(gA[s] + (size_t)t * 32, &As[bb][(s * 512 + tid) * 8]);
    };
    auto stage_b = [&](int t) {
        const int bb = t & 3;
        async_copy16(gB0 + (size_t)t * 32, &Bs[bb][tid * 8]);
        if (heavy) async_copy16(gB1 + (size_t)t * 32, &Bs[bb][(512 + tid) * 8]);
    };
    auto boundary = [&]() {   // depth-3: oldest tile landed, 2 tiles in flight
        if (heavy) wait_vm_bar<2 * LH>();
        else       wait_vm_bar<2 * LL>();
    };
    auto tail1 = [&]() {      // 1 tile in flight
        if (heavy) wait_vm_bar<LH>();
        else       wait_vm_bar<LL>();
    };

    auto tile_body = [&](int t, bool doStage) {
        const int bb = t & 3;
        const bf16* as = &As[bb][0];
        const bf16* bs = &Bs[bb][0];
        bf16x8 bfr[NT], af[MT / 2];
#pragma unroll
        for (int nt = 0; nt < NT; nt++)
            bfr[nt] = *(const bf16x8*)(bs + (wn * WN + nt * 16 + c) * 32 + rdOff);
#pragma unroll
        for (int mt = 0; mt < MT / 2; mt++)
            af[mt] = *(const bf16x8*)(as + (wm * WM + mt * 16 + c) * 32 + rdOff);
        if (doStage) stage_a(t + 3);
        __builtin_amdgcn_s_setprio(1);
#pragma unroll
        for (int mt = 0; mt < MT / 2; mt++)
#pragma unroll
            for (int nt = 0; nt < NT; nt++)
                acc[mt][nt] = __builtin_amdgcn_mfma_f32_16x16x32_bf16(af[mt], bfr[nt],
                                                                      acc[mt][nt], 0, 0, 0);
        __builtin_amdgcn_s_setprio(0);
#pragma unroll
        for (int mt = 0; mt < MT / 2; mt++)
            af[mt] = *(const bf16x8*)(as + (wm * WM + (MT / 2 + mt) * 16 + c) * 32 + rdOff);
        if (doStage) stage_b(t + 3);
        __builtin_amdgcn_s_setprio(1);
#pragma unroll
        for (int mt = 0; mt < MT / 2; mt++)
#pragma unroll
            for (int nt = 0; nt < NT; nt++)
                acc[MT / 2 + mt][nt] = __builtin_amdgcn_mfma_f32_16x16x32_bf16(
                    af[mt], bfr[nt], acc[MT / 2 + mt][nt], 0, 0, 0);
        __builtin_amdgcn_s_setprio(0);
    };

    const int NTK = K >> 5;   // K-tiles of 32 (NTK >= 4)
    stage_a(0); stage_b(0);
    stage_a(1); stage_b(1);
    stage_a(2); stage_b(2);
    boundary();   // t0 landed; t1,t2 in flight

    for (int t = 0; t < NTK - 3; ++t) {
        tile_body(t, true);    // stages t+3
        boundary();
    }
    tile_body(NTK - 3, false);
    tail1();
    tile_body(NTK - 2, false);
    wait_vm_bar<0>();
    tile_body(NTK - 1, false);

#pragma unroll
    for (int mt = 0; mt < MT; mt++)
#pragma unroll
        for (int nt = 0; nt < NT; nt++)
#pragma unroll
            for (int r = 0; r < 4; r++) {
                int row = mBase + wm * WM + mt * 16 + quad * 4 + r;
                int col = nBase + wn * WN + nt * 16 + c;
                if (OUTF32)
                    ((float*)Cout)[(size_t)row * N + col] = acc[mt][nt][r];
                else
                    ((bf16*)Cout)[(size_t)row * N + col] = __float2bfloat16(acc[mt][nt][r]);
            }
}

// ---------------- RoPE (K only), in place on bf16 ----------------
__global__ __launch_bounds__(256) void rope_kernel(bf16* __restrict__ X, int heads, int rowStride) {
    int idx = blockIdx.x * 256 + threadIdx.x;
    int d = idx & 63;
    int h = (idx >> 6) % heads;
    int row = idx / (heads * 64);
    int t = row & 2047;
    float theta = exp2f(-(float)d * 0.20762050593045827f);  // 10000^(-d/64)
    float ang = (float)t * theta;
    float sv, cv;
    __sincosf(ang, &sv, &cv);
    bf16* p = X + (size_t)row * rowStride + h * 128 + d;
    float x1 = __bfloat162float(p[0]);
    float x2 = __bfloat162float(p[64]);
    p[0]  = __float2bfloat16(x1 * cv - x2 * sv);
    p[64] = __float2bfloat16(x2 * cv + x1 * sv);
}

// ------- V transpose: QKV V-block [t][d] -> Vtg [b*4+kvh][d=128][t=2048] -------
// Keys are sigma-permuted within each 32-key chunk so that the flash kernel's
// in-register P fragment (from swapped QK^T) lines up with V's MFMA k-slots:
// Vtg position p holds key sigma(p), sigma(quad*8+j) = (j>=4?16:0)+quad*4+(j&3).
// Writing: key k lands at position sigma^{-1}(k) = ((g&3)*2 + g>>2)*4 + (k&3), g=k>>2.
__global__ __launch_bounds__(256) void vtrans(const bf16* __restrict__ QKV,
                                              bf16* __restrict__ Vtg) {
    __shared__ bf16 tile[32][34];
    const int bh = blockIdx.z;
    const int b = bh >> 2, kvh = bh & 3;
    const int t0 = blockIdx.x * 32, d0 = blockIdx.y * 32;
    const bf16* src = QKV + (size_t)b * 2048 * 3072 + 2560 + kvh * 128;
    const int tx = threadIdx.x;
    for (int j = threadIdx.y; j < 32; j += 8)
        tile[j][tx] = src[(size_t)(t0 + j) * 3072 + d0 + tx];
    __syncthreads();
    bf16* dst = Vtg + (size_t)bh * 128 * 2048;
    const int g = tx >> 2;
    const int txp = (((g & 3) << 1) | (g >> 2)) * 4 + (tx & 3);   // sigma^{-1}(tx)
    for (int j = threadIdx.y; j < 32; j += 8)
        dst[(size_t)(d0 + j) * 2048 + t0 + txp] = tile[tx][j];
}

// ---------------- flash attention v6: swapped QK^T, in-register P ----------------
// R5-proven version (4 blocks/CU, 37 KB LDS). R7's double-buffer REGRESSED
// (occupancy 4->2 killed TLP latency hiding) — keep single-buffered staging.
__global__ __launch_bounds__(256, 4) void flash_attn5(const bf16* __restrict__ QKV,
                                                      const bf16* __restrict__ Vtg,
                                                      bf16* __restrict__ Slot0,
                                                      bf16* __restrict__ Slot1,
                                                      float* __restrict__ Ls) {
    const int T = 2048, STR = 3072;
    __shared__ bf16 Ks[4 * 64 * 32];      // 16 KB  [d-chunk][key 64][32]
    __shared__ bf16 Vs[2 * 128 * 32];     // 16 KB  [key-chunk][d 128][32]
    const int b = blockIdx.z, h = blockIdx.y;
    const int pj = blockIdx.x >> 1, s = blockIdx.x & 1;
    const int kvh = h >> 2;
    const int tid = threadIdx.x, wave = tid >> 6, lane = tid & 63;
    const int c = lane & 15, quad = lane >> 4;
    const float C2 = 0.12751541717525597f;  // (1/sqrt(128)) * log2(e), folded into Q

    const bf16* Kg = QKV + (size_t)b * T * STR + 2048 + kvh * 128;
    const bf16* Vg = Vtg + (size_t)(b * 4 + kvh) * 128 * 2048;
    const int srow = tid >> 2;
    const int xcol = ((tid & 3) ^ ((tid >> 3) & 3)) << 3;   // swizzled staging chunk
    const int koff = (quad ^ ((c >> 1) & 3)) << 3;          // swizzled read offset
    const int qa = 31 - pj;

    auto run_part = [&](int qtile, int ktlo, int kthi, bf16* slot, int lsSlot) {
        const int q0 = qtile * 64;
        // Q frags + RoPE + scale fold, in-register
        bf16x8 qf[4];
        {
            const bf16* qp = QKV + ((size_t)b * T + q0 + wave * 16 + c) * STR + h * 128 + quad * 8;
#pragma unroll
            for (int ks = 0; ks < 4; ks++) qf[ks] = *(const bf16x8*)(qp + ks * 32);
            const float t = (float)(q0 + wave * 16 + c);
#pragma unroll
            for (int ks = 0; ks < 2; ks++)
#pragma unroll
                for (int j = 0; j < 8; j++) {
                    int d = ks * 32 + quad * 8 + j;
                    float theta = exp2f((float)d * -0.20762050593045827f);
                    float sv, cv;
                    __sincosf(t * theta, &sv, &cv);
                    float lo = __bfloat162float(((const bf16*)&qf[ks])[j]);
                    float hi = __bfloat162float(((const bf16*)&qf[ks + 2])[j]);
                    ((bf16*)&qf[ks])[j]     = __float2bfloat16((lo * cv - hi * sv) * C2);
                    ((bf16*)&qf[ks + 2])[j] = __float2bfloat16((hi * cv + lo * sv) * C2);
                }
        }
        floatx4 accO[8];
#pragma unroll
        for (int nt = 0; nt < 8; nt++) accO[nt] = (floatx4){0.f, 0.f, 0.f, 0.f};
        float lsum = 0.f;

        for (int kt = ktlo; kt < kthi; kt++) {
            const int kt0 = kt * 64;
#pragma unroll
            for (int it = 0; it < 4; it++) {
                async_copy16(Kg + (size_t)(kt0 + srow) * STR + it * 32 + xcol,
                             Ks + it * 2048 + wave * 512);
                async_copy16(Vg + (size_t)((it & 1) * 64 + srow) * 2048 + kt0 + (it >> 1) * 32 + xcol,
                             Vs + it * 2048 + wave * 512);
            }
            __syncthreads();
            // swapped QK^T: sf[nt] = S^T[key nt*16+quad*4+r][q = c]
            floatx4 sf[4];
#pragma unroll
            for (int nt = 0; nt < 4; nt++) sf[nt] = (floatx4){0.f, 0.f, 0.f, 0.f};
#pragma unroll
            for (int ks = 0; ks < 4; ks++)
#pragma unroll
                for (int nt = 0; nt < 4; nt++) {
                    bf16x8 kf = *(const bf16x8*)(Ks + ks * 2048 + (nt * 16 + c) * 32 + koff);
                    sf[nt] = __builtin_amdgcn_mfma_f32_16x16x32_bf16(kf, qf[ks], sf[nt], 0, 0, 0);
                }
            // softmax numerator, fully in-register (lane c owns q-row q0+wave*16+c)
            if (kt == qtile) {
                const int qrel = wave * 16 + c;
#pragma unroll
                for (int nt = 0; nt < 4; nt++)
#pragma unroll
                    for (int r = 0; r < 4; r++) {
                        float p = exp2f(sf[nt][r]);
                        if (nt * 16 + quad * 4 + r > qrel) p = 0.f;
                        lsum += p;
                        sf[nt][r] = p;
                    }
            } else {
#pragma unroll
                for (int nt = 0; nt < 4; nt++)
#pragma unroll
                    for (int r = 0; r < 4; r++) {
                        float p = exp2f(sf[nt][r]);
                        lsum += p;
                        sf[nt][r] = p;
                    }
            }
            // PV: pack P in-register; V key-slots sigma-matched by vtrans
#pragma unroll
            for (int kc = 0; kc < 2; kc++) {
                bf16x8 pf;
#pragma unroll
                for (int j = 0; j < 4; j++) {
                    ((bf16*)&pf)[j]     = __float2bfloat16(sf[2 * kc][j]);
                    ((bf16*)&pf)[4 + j] = __float2bfloat16(sf[2 * kc + 1][j]);
                }
#pragma unroll
                for (int nt = 0; nt < 8; nt++) {
                    bf16x8 vf = *(const bf16x8*)(Vs + kc * 4096 + (nt * 16 + c) * 32 + koff);
                    accO[nt] = __builtin_amdgcn_mfma_f32_16x16x32_bf16(pf, vf, accO[nt], 0, 0, 0);
                }
            }
            __syncthreads();
        }
        // row-sum: reduce over the 4 quads holding this q-row's keys
        {
            float v = lsum;
            v += __shfl_xor(v, 16);
            v += __shfl_xor(v, 32);
            if (quad == 0)
                Ls[(size_t)lsSlot * 65536 + ((size_t)(b * 16 + h) * 32 + qtile) * 64
                   + wave * 16 + c] = v;
        }
        const size_t orow = (size_t)b * T + q0 + wave * 16 + quad * 4;
#pragma unroll
        for (int nt = 0; nt < 8; nt++)
#pragma unroll
            for (int r = 0; r < 4; r++)
                slot[(orow + r) * 2048 + h * 128 + nt * 16 + c] =
                    __float2bfloat16(accO[nt][r]);
    };

    if (s == 0) {
        run_part(qa, 0, 17, Slot0, 0);
    } else {
        run_part(qa, 17, 32 - pj, Slot1, 1);   // empty for pj==15 -> writes zeros
        run_part(pj, 0, pj + 1, Slot0, 0);
    }
}

// ---------------- merge partials: AO = (Slot0 + Slot1) / (l0 + l1) ----------------
__global__ __launch_bounds__(256) void attn_merge(bf16* __restrict__ AO,
                                                  const bf16* __restrict__ P1,
                                                  const float* __restrict__ Ls) {
    int i = blockIdx.x * 256 + threadIdx.x;   // 1,048,576 threads, 8 cols each
    int row = i >> 8;                         // 0..4095
    int cg = (i & 255) << 3;                  // col 0..2040 step 8
    int b = row >> 11, t = row & 2047;
    int qtile = t >> 6;
    int h = cg >> 7;
    size_t off = (size_t)row * 2048 + cg;
    size_t li = ((size_t)(b * 16 + h) * 32 + qtile) * 64 + (t & 63);
    bf16x8 a0 = *(const bf16x8*)(AO + off);
    float l = Ls[li];
    float acc[8];
#pragma unroll
    for (int j = 0; j < 8; j++) acc[j] = __bfloat162float(((const bf16*)&a0)[j]);
    if (qtile >= 16) {   // q-tiles 16..31 have a second partial
        bf16x8 a1 = *(const bf16x8*)(P1 + off);
        l += Ls[65536 + li];
#pragma unroll
        for (int j = 0; j < 8; j++) acc[j] += __bfloat162float(((const bf16*)&a1)[j]);
    }
    float inv = 1.0f / l;
    bf16x8 o;
#pragma unroll
    for (int j = 0; j < 8; j++) ((bf16*)&o)[j] = __float2bfloat16(acc[j] * inv);
    *(bf16x8*)(AO + off) = o;
}

extern "C" void kernel_launch(void* const* d_in, const int* in_sizes, int n_in,
                              void* d_out, int out_size, void* d_ws, size_t ws_size,
                              hipStream_t stream) {
    const float* x  = (const float*)d_in[0];
    const float* Wq = (const float*)d_in[1];
    const float* Wk = (const float*)d_in[2];
    const float* Wv = (const float*)d_in[3];
    const float* Wo = (const float*)d_in[4];

    char* ws = (char*)d_ws;
    bf16* xb   = (bf16*)(ws);                 // [4096][2048] (dead after QKV GEMM)
    bf16* Vtg  = (bf16*)(ws);                 // reuses xb: [8][128][2048] = 4 MB
    bf16* Slt1 = (bf16*)(ws + 4194304);       // 16.78 MB, overlays dead xb-tail + Wt
    float* Ls  = (float*)(ws + 20971520);     // 0.5 MB lsum[2][b][h][qtile][64]
    bf16* Wt   = (bf16*)(ws + 16777216);      // [3072][2048] Wq|Wk|Wv (dead before flash)
    bf16* Wot  = (bf16*)(ws + 29360128);      // [2048][2048] (live until out-proj)
    bf16* QKV  = (bf16*)(ws + 37748736);      // [4096][3072]
    bf16* AO   = (bf16*)(ws + 62914560);      // [4096][2048] = partial Slot0, merged in place

    cast_f32_bf16<<<8192, 256, 0, stream>>>(x, xb, 2097152);
    cast_transpose<<<dim3(64, 64), dim3(32, 8), 0, stream>>>(Wq, Wt, 2048, 2048);
    cast_transpose<<<dim3(16, 64), dim3(32, 8), 0, stream>>>(Wk, Wt + 2048 * 2048, 2048, 512);
    cast_transpose<<<dim3(16, 64), dim3(32, 8), 0, stream>>>(Wv, Wt + 2560 * 2048, 2048, 512);
    cast_transpose<<<dim3(64, 64), dim3(32, 8), 0, stream>>>(Wo, Wot, 2048, 2048);

    // QKV projection: 256^2 kernel, depth-3 prefetch, grid 12x16 = 192 blocks
    gemm256<<<dim3(12, 16), 512, 0, stream>>>(xb, Wt, QKV, 4096, 3072, 2048);

    // RoPE on K only (Q-RoPE fused into flash_attn5)
    rope_kernel<<<4096, 256, 0, stream>>>(QKV + 2048, 4, 3072);

    // V transpose (into Vtg at ws base), sigma-permuted keys within 32-chunks
    vtrans<<<dim3(64, 4, 8), dim3(32, 8), 0, stream>>>(QKV, Vtg);

    // split-kv flash attention: 16 pairs x 2 splits x 16 heads x 2 batch = 1024 uniform blocks
    flash_attn5<<<dim3(32, 16, 2), 256, 0, stream>>>(QKV, Vtg, AO, Slt1, Ls);

    // merge partials -> AO (in place)
    attn_merge<<<4096, 256, 0, stream>>>(AO, Slt1, Ls);

    // output projection: 128x256 tiles, depth-3 prefetch -> grid 8x32 = 256 blocks
    gemm256g<128, 256, true><<<dim3(8, 32), 512, 0, stream>>>(AO, Wot, d_out, 4096, 2048, 2048);
}

// Round 9
// 298.188 us; speedup vs baseline: 1.0825x; 1.0251x over previous
//
#include <hip/hip_runtime.h>
#include <hip/hip_bf16.h>
#include <math.h>

typedef __hip_bfloat16 bf16;
typedef __attribute__((ext_vector_type(8))) short bf16x8;   // 8 bf16 = 4 VGPRs (MFMA A/B frag)
typedef __attribute__((ext_vector_type(4))) float floatx4;  // MFMA C/D frag

// async global->LDS, 16B per lane. LDS dest = wave-uniform base + lane*16.
__device__ __forceinline__ void async_copy16(const bf16* g, bf16* l) {
    __builtin_amdgcn_global_load_lds(
        (__attribute__((address_space(1))) void*)(void*)g,
        (__attribute__((address_space(3))) void*)(void*)l,
        16, 0, 0);
}

template <int N>
__device__ __forceinline__ void wait_vm_bar() {
    if constexpr (N == 0) asm volatile("s_waitcnt vmcnt(0)\n\ts_barrier" ::: "memory");
    else if constexpr (N == 1) asm volatile("s_waitcnt vmcnt(1)\n\ts_barrier" ::: "memory");
    else if constexpr (N == 2) asm volatile("s_waitcnt vmcnt(2)\n\ts_barrier" ::: "memory");
    else if constexpr (N == 3) asm volatile("s_waitcnt vmcnt(3)\n\ts_barrier" ::: "memory");
    else if constexpr (N == 4) asm volatile("s_waitcnt vmcnt(4)\n\ts_barrier" ::: "memory");
    else if constexpr (N == 5) asm volatile("s_waitcnt vmcnt(5)\n\ts_barrier" ::: "memory");
    else if constexpr (N == 6) asm volatile("s_waitcnt vmcnt(6)\n\ts_barrier" ::: "memory");
    else if constexpr (N == 7) asm volatile("s_waitcnt vmcnt(7)\n\ts_barrier" ::: "memory");
    else if constexpr (N == 8) asm volatile("s_waitcnt vmcnt(8)\n\ts_barrier" ::: "memory");
}

// ---------------- fused prep: cast x + all 4 weight cast-transposes ----------------
// Block ranges: [0,8192) cast x (float4); [8192,12288) Wq; [12288,13312) Wk;
// [13312,14336) Wv; [14336,18432) Wo. Branch is blockIdx-uniform.
// R9: fuses 5 kernels -> 1 (launch-overhead reduction).
__global__ __launch_bounds__(256) void prep_kernel(const float* __restrict__ x,
                                                   bf16* __restrict__ xb,
                                                   const float* __restrict__ Wq,
                                                   const float* __restrict__ Wk,
                                                   const float* __restrict__ Wv,
                                                   const float* __restrict__ Wo,
                                                   bf16* __restrict__ Wt,
                                                   bf16* __restrict__ Wot) {
    const int tid = threadIdx.x;
    int bid = blockIdx.x;
    if (bid < 8192) {
        int i = bid * 256 + tid;   // 2,097,152 float4s total
        float4 v = ((const float4*)x)[i];
        union { ushort4 u; bf16 b[4]; } o;
        o.b[0] = __float2bfloat16(v.x);
        o.b[1] = __float2bfloat16(v.y);
        o.b[2] = __float2bfloat16(v.z);
        o.b[3] = __float2bfloat16(v.w);
        ((ushort4*)xb)[i] = o.u;
        return;
    }
    bid -= 8192;
    __shared__ float tile[32][33];
    const float* in;
    bf16* out;
    int N, bx, by;
    if (bid < 4096)      { in = Wq; out = Wt;               N = 2048; bx = bid & 63; by = bid >> 6; }
    else if (bid < 5120) { int b2 = bid - 4096; in = Wk; out = Wt + 2048 * 2048; N = 512; bx = b2 & 15; by = b2 >> 4; }
    else if (bid < 6144) { int b2 = bid - 5120; in = Wv; out = Wt + 2560 * 2048; N = 512; bx = b2 & 15; by = b2 >> 4; }
    else                 { int b2 = bid - 6144; in = Wo; out = Wot;              N = 2048; bx = b2 & 63; by = b2 >> 6; }
    const int K = 2048;
    const int nb = bx * 32, kb = by * 32;
    const int tx = tid & 31, ty = tid >> 5;
    for (int j = ty; j < 32; j += 8)
        tile[j][tx] = in[(size_t)(kb + j) * N + nb + tx];
    __syncthreads();
    for (int j = ty; j < 32; j += 8)
        out[(size_t)(nb + j) * K + kb + tx] = __float2bfloat16(tile[tx][j]);
}

// ---------------- 256x256 deep-pipelined bf16 GEMM (T3+T4+T5) ----------------
// R8 config (measured 63.2 us on QKV): depth-3 prefetch, BK=32, 4-deep LDS ring,
// boundary vmcnt(8). R6's per-phase barriers REGRESSED — do not re-add.
__global__ __launch_bounds__(512) void gemm256(const bf16* __restrict__ A,
                                               const bf16* __restrict__ Bt,
                                               bf16* __restrict__ C,
                                               int M, int N, int K) {
    __shared__ bf16 As[4][256 * 32];   // 64 KB
    __shared__ bf16 Bs[4][256 * 32];   // 64 KB
    const int tid = threadIdx.x;
    const int wave = tid >> 6, lane = tid & 63;
    const int c = lane & 15, quad = lane >> 4;
    const int wm = wave >> 2, wn = wave & 3;          // 2 x 4 wave grid
    const int mBase = blockIdx.y * 256, nBase = blockIdx.x * 256;
    const int rdOff = (quad ^ ((c >> 1) & 3)) << 3;   // swizzled read offset (elements)

    const bf16* gAs[2];
    const bf16* gBs[2];
#pragma unroll
    for (int i = 0; i < 2; i++) {
        int ci = i * 512 + tid;
        int r = ci >> 2;
        int sc = (ci & 3) ^ ((r >> 1) & 3);
        gAs[i] = A + (size_t)(mBase + r) * K + sc * 8;
        gBs[i] = Bt + (size_t)(nBase + r) * K + sc * 8;
    }
    const int ldsW = wave * 512;   // wave-uniform element offset within a half

    floatx4 acc[8][4];
#pragma unroll
    for (int mt = 0; mt < 8; mt++)
#pragma unroll
        for (int nt = 0; nt < 4; nt++) acc[mt][nt] = (floatx4){0.f, 0.f, 0.f, 0.f};

    auto stage_half = [&](int t, int i) {
        const int bb = t & 3;
        const int lo = i * 4096 + ldsW;
        async_copy16(gAs[i] + (size_t)t * 32, &As[bb][0] + lo);
        async_copy16(gBs[i] + (size_t)t * 32, &Bs[bb][0] + lo);
    };

    auto tile_body = [&](int t, bool doStage) {
        const int bb = t & 3;
        const bf16* as = &As[bb][0];
        const bf16* bs = &Bs[bb][0];
        bf16x8 bfr[4], af[4];
#pragma unroll
        for (int nt = 0; nt < 4; nt++)
            bfr[nt] = *(const bf16x8*)(bs + (wn * 64 + nt * 16 + c) * 32 + rdOff);
#pragma unroll
        for (int mt = 0; mt < 4; mt++)
            af[mt] = *(const bf16x8*)(as + (wm * 128 + mt * 16 + c) * 32 + rdOff);
        if (doStage) stage_half(t + 3, 0);
        __builtin_amdgcn_s_setprio(1);
#pragma unroll
        for (int mt = 0; mt < 4; mt++)
#pragma unroll
            for (int nt = 0; nt < 4; nt++)
                acc[mt][nt] = __builtin_amdgcn_mfma_f32_16x16x32_bf16(af[mt], bfr[nt],
                                                                      acc[mt][nt], 0, 0, 0);
        __builtin_amdgcn_s_setprio(0);
#pragma unroll
        for (int mt = 0; mt < 4; mt++)
            af[mt] = *(const bf16x8*)(as + (wm * 128 + 64 + mt * 16 + c) * 32 + rdOff);
        if (doStage) stage_half(t + 3, 1);
        __builtin_amdgcn_s_setprio(1);
#pragma unroll
        for (int mt = 0; mt < 4; mt++)
#pragma unroll
            for (int nt = 0; nt < 4; nt++)
                acc[4 + mt][nt] = __builtin_amdgcn_mfma_f32_16x16x32_bf16(af[mt], bfr[nt],
                                                                          acc[4 + mt][nt], 0, 0, 0);
        __builtin_amdgcn_s_setprio(0);
    };

    const int NT = K >> 5;   // K-tiles of 32 (NT >= 4)
    stage_half(0, 0); stage_half(0, 1);
    stage_half(1, 0); stage_half(1, 1);
    stage_half(2, 0); stage_half(2, 1);
    wait_vm_bar<8>();   // t0 landed; t1,t2 in flight

    for (int t = 0; t < NT - 3; ++t) {
        tile_body(t, true);          // stages t+3
        wait_vm_bar<8>();            // t+1 landed; t+2,t+3 in flight
    }
    tile_body(NT - 3, false);
    wait_vm_bar<4>();                // NT-2 landed; NT-1 in flight
    tile_body(NT - 2, false);
    wait_vm_bar<0>();                // NT-1 landed
    tile_body(NT - 1, false);

#pragma unroll
    for (int mt = 0; mt < 8; mt++)
#pragma unroll
        for (int nt = 0; nt < 4; nt++)
#pragma unroll
            for (int r = 0; r < 4; r++) {
                int row = mBase + wm * 128 + mt * 16 + quad * 4 + r;
                int col = nBase + wn * 64 + nt * 16 + c;
                C[(size_t)row * N + col] = __float2bfloat16(acc[mt][nt][r]);
            }
}

// ------- generic deep-pipelined GEMM (T1+T3+T4+T5), 8 waves (2M x 4N) -------
// Out-proj (BM=128, BN=256), R5-proven depth-2 config (depth-3 cost ~3 us in R8).
template <int BM, int BN, bool OUTF32>
__global__ __launch_bounds__(512) void gemm256g(const bf16* __restrict__ A,
                                                const bf16* __restrict__ Bt,
                                                void* __restrict__ Cout,
                                                int M, int N, int K) {
    constexpr int CA = BM * 4;              // 16B chunks per A k-tile
    constexpr int CB = BN * 4;
    constexpr int A_LPT = CA / 512;         // uniform A loads per thread (1 or 2)
    constexpr int EXTRA = CB - 512;         // threads issuing a 2nd B load
    constexpr int WM = BM / 2, WN = BN / 4; // per-wave output tile
    constexpr int MT = WM / 16, NT = WN / 16;
    __shared__ bf16 As[4][BM * 32];
    __shared__ bf16 Bs[4][BN * 32];
    const int tid = threadIdx.x;
    const int wave = tid >> 6, lane = tid & 63;
    const int c = lane & 15, quad = lane >> 4;
    const int wm = wave >> 2, wn = wave & 3;

    // XCD-aware swizzle (bijective: grid total divisible by 8)
    const int GX = gridDim.x;
    const int GB = GX * gridDim.y;
    int bid = blockIdx.y * GX + blockIdx.x;
    bid = (bid & 7) * (GB >> 3) + (bid >> 3);
    const int mBase = (bid / GX) * BM, nBase = (bid % GX) * BN;

    const int rdOff = (quad ^ ((c >> 1) & 3)) << 3;   // swizzled read offset (elems)
    const bool heavy = (EXTRA == 512) ? true : (tid < EXTRA);   // wave-uniform

    const bf16* gA[A_LPT];
#pragma unroll
    for (int s = 0; s < A_LPT; s++) {
        int ci = s * 512 + tid;
        int r = ci >> 2;
        int sc = (ci & 3) ^ ((r >> 1) & 3);
        gA[s] = A + (size_t)(mBase + r) * K + sc * 8;
    }
    const bf16* gB0;
    {
        int r = tid >> 2;
        int sc = (tid & 3) ^ ((r >> 1) & 3);
        gB0 = Bt + (size_t)(nBase + r) * K + sc * 8;
    }
    const bf16* gB1 = nullptr;
    if (heavy) {
        int ci = 512 + tid;
        int r = ci >> 2;
        int sc = (ci & 3) ^ ((r >> 1) & 3);
        gB1 = Bt + (size_t)(nBase + r) * K + sc * 8;
    }

    floatx4 acc[MT][NT];
#pragma unroll
    for (int mt = 0; mt < MT; mt++)
#pragma unroll
        for (int nt = 0; nt < NT; nt++) acc[mt][nt] = (floatx4){0.f, 0.f, 0.f, 0.f};

    auto stage_a = [&](int t) {
        const int bb = t & 3;
#pragma unroll
        for (int s = 0; s < A_LPT; s++)
            async_copy16(gA[s] + (size_t)t * 32, &As[bb][(s * 512 + tid) * 8]);
    };
    auto stage_b = [&](int t) {
        const int bb = t & 3;
        async_copy16(gB0 + (size_t)t * 32, &Bs[bb][tid * 8]);
        if (heavy) async_copy16(gB1 + (size_t)t * 32, &Bs[bb][(512 + tid) * 8]);
    };
    auto boundary = [&]() {   // counted: tile t+1 landed, t+2's own loads in flight
        if (heavy) wait_vm_bar<A_LPT + 2>();
        else       wait_vm_bar<A_LPT + 1>();
    };

    auto tile_body = [&](int t, bool doStage) {
        const int bb = t & 3;
        const bf16* as = &As[bb][0];
        const bf16* bs = &Bs[bb][0];
        bf16x8 bfr[NT], af[MT / 2];
#pragma unroll
        for (int nt = 0; nt < NT; nt++)
            bfr[nt] = *(const bf16x8*)(bs + (wn * WN + nt * 16 + c) * 32 + rdOff);
#pragma unroll
        for (int mt = 0; mt < MT / 2; mt++)
            af[mt] = *(const bf16x8*)(as + (wm * WM + mt * 16 + c) * 32 + rdOff);
        if (doStage) stage_a(t + 2);
        __builtin_amdgcn_s_setprio(1);
#pragma unroll
        for (int mt = 0; mt < MT / 2; mt++)
#pragma unroll
            for (int nt = 0; nt < NT; nt++)
                acc[mt][nt] = __builtin_amdgcn_mfma_f32_16x16x32_bf16(af[mt], bfr[nt],
                                                                      acc[mt][nt], 0, 0, 0);
        __builtin_amdgcn_s_setprio(0);
#pragma unroll
        for (int mt = 0; mt < MT / 2; mt++)
            af[mt] = *(const bf16x8*)(as + (wm * WM + (MT / 2 + mt) * 16 + c) * 32 + rdOff);
        if (doStage) stage_b(t + 2);
        __builtin_amdgcn_s_setprio(1);
#pragma unroll
        for (int mt = 0; mt < MT / 2; mt++)
#pragma unroll
            for (int nt = 0; nt < NT; nt++)
                acc[MT / 2 + mt][nt] = __builtin_amdgcn_mfma_f32_16x16x32_bf16(
                    af[mt], bfr[nt], acc[MT / 2 + mt][nt], 0, 0, 0);
        __builtin_amdgcn_s_setprio(0);
    };

    const int NTK = K >> 5;   // K-tiles of 32
    stage_a(0); stage_b(0);
    stage_a(1); stage_b(1);
    boundary();

    for (int t = 0; t < NTK - 2; ++t) {
        tile_body(t, true);
        boundary();
    }
    tile_body(NTK - 2, false);
    wait_vm_bar<0>();   // epilogue drain
    tile_body(NTK - 1, false);

#pragma unroll
    for (int mt = 0; mt < MT; mt++)
#pragma unroll
        for (int nt = 0; nt < NT; nt++)
#pragma unroll
            for (int r = 0; r < 4; r++) {
                int row = mBase + wm * WM + mt * 16 + quad * 4 + r;
                int col = nBase + wn * WN + nt * 16 + c;
                if (OUTF32)
                    ((float*)Cout)[(size_t)row * N + col] = acc[mt][nt][r];
                else
                    ((bf16*)Cout)[(size_t)row * N + col] = __float2bfloat16(acc[mt][nt][r]);
            }
}

// ---------------- fused RoPE(K) + V transpose ----------------
// Blocks [0,4096): rope on K (in place). Blocks [4096,6144): vtrans with
// sigma-permuted keys. Disjoint data (K block vs V block of QKV) -> no ordering
// hazard. R9: fuses 2 kernels -> 1.
__global__ __launch_bounds__(256) void rope_vtrans(bf16* __restrict__ QKV,
                                                   bf16* __restrict__ Vtg) {
    const int tid = threadIdx.x;
    int bid = blockIdx.x;
    if (bid < 4096) {
        // RoPE on K: X = QKV + 2048, heads = 4, rowStride = 3072
        int idx = bid * 256 + tid;
        int d = idx & 63;
        int h = (idx >> 6) & 3;
        int row = idx >> 8;
        int t = row & 2047;
        float theta = exp2f(-(float)d * 0.20762050593045827f);  // 10000^(-d/64)
        float ang = (float)t * theta;
        float sv, cv;
        __sincosf(ang, &sv, &cv);
        bf16* p = QKV + 2048 + (size_t)row * 3072 + h * 128 + d;
        float x1 = __bfloat162float(p[0]);
        float x2 = __bfloat162float(p[64]);
        p[0]  = __float2bfloat16(x1 * cv - x2 * sv);
        p[64] = __float2bfloat16(x2 * cv + x1 * sv);
        return;
    }
    bid -= 4096;
    __shared__ bf16 tile[32][34];
    const int bx = bid & 63, by = (bid >> 6) & 3, bh = bid >> 8;
    const int b = bh >> 2, kvh = bh & 3;
    const int t0 = bx * 32, d0 = by * 32;
    const bf16* src = QKV + (size_t)b * 2048 * 3072 + 2560 + kvh * 128;
    const int tx = tid & 31, ty = tid >> 5;
    for (int j = ty; j < 32; j += 8)
        tile[j][tx] = src[(size_t)(t0 + j) * 3072 + d0 + tx];
    __syncthreads();
    bf16* dst = Vtg + (size_t)bh * 128 * 2048;
    const int g = tx >> 2;
    const int txp = (((g & 3) << 1) | (g >> 2)) * 4 + (tx & 3);   // sigma^{-1}(tx)
    for (int j = ty; j < 32; j += 8)
        dst[(size_t)(d0 + j) * 2048 + t0 + txp] = tile[tx][j];
}

// ---------------- flash attention v6: swapped QK^T, in-register P ----------------
// R5-proven version (4 blocks/CU, 37 KB LDS). R7's double-buffer REGRESSED
// (occupancy 4->2 killed TLP latency hiding) — keep single-buffered staging.
__global__ __launch_bounds__(256, 4) void flash_attn5(const bf16* __restrict__ QKV,
                                                      const bf16* __restrict__ Vtg,
                                                      bf16* __restrict__ Slot0,
                                                      bf16* __restrict__ Slot1,
                                                      float* __restrict__ Ls) {
    const int T = 2048, STR = 3072;
    __shared__ bf16 Ks[4 * 64 * 32];      // 16 KB  [d-chunk][key 64][32]
    __shared__ bf16 Vs[2 * 128 * 32];     // 16 KB  [key-chunk][d 128][32]
    const int b = blockIdx.z, h = blockIdx.y;
    const int pj = blockIdx.x >> 1, s = blockIdx.x & 1;
    const int kvh = h >> 2;
    const int tid = threadIdx.x, wave = tid >> 6, lane = tid & 63;
    const int c = lane & 15, quad = lane >> 4;
    const float C2 = 0.12751541717525597f;  // (1/sqrt(128)) * log2(e), folded into Q

    const bf16* Kg = QKV + (size_t)b * T * STR + 2048 + kvh * 128;
    const bf16* Vg = Vtg + (size_t)(b * 4 + kvh) * 128 * 2048;
    const int srow = tid >> 2;
    const int xcol = ((tid & 3) ^ ((tid >> 3) & 3)) << 3;   // swizzled staging chunk
    const int koff = (quad ^ ((c >> 1) & 3)) << 3;          // swizzled read offset
    const int qa = 31 - pj;

    auto run_part = [&](int qtile, int ktlo, int kthi, bf16* slot, int lsSlot) {
        const int q0 = qtile * 64;
        // Q frags + RoPE + scale fold, in-register
        bf16x8 qf[4];
        {
            const bf16* qp = QKV + ((size_t)b * T + q0 + wave * 16 + c) * STR + h * 128 + quad * 8;
#pragma unroll
            for (int ks = 0; ks < 4; ks++) qf[ks] = *(const bf16x8*)(qp + ks * 32);
            const float t = (float)(q0 + wave * 16 + c);
#pragma unroll
            for (int ks = 0; ks < 2; ks++)
#pragma unroll
                for (int j = 0; j < 8; j++) {
                    int d = ks * 32 + quad * 8 + j;
                    float theta = exp2f((float)d * -0.20762050593045827f);
                    float sv, cv;
                    __sincosf(t * theta, &sv, &cv);
                    float lo = __bfloat162float(((const bf16*)&qf[ks])[j]);
                    float hi = __bfloat162float(((const bf16*)&qf[ks + 2])[j]);
                    ((bf16*)&qf[ks])[j]     = __float2bfloat16((lo * cv - hi * sv) * C2);
                    ((bf16*)&qf[ks + 2])[j] = __float2bfloat16((hi * cv + lo * sv) * C2);
                }
        }
        floatx4 accO[8];
#pragma unroll
        for (int nt = 0; nt < 8; nt++) accO[nt] = (floatx4){0.f, 0.f, 0.f, 0.f};
        float lsum = 0.f;

        for (int kt = ktlo; kt < kthi; kt++) {
            const int kt0 = kt * 64;
#pragma unroll
            for (int it = 0; it < 4; it++) {
                async_copy16(Kg + (size_t)(kt0 + srow) * STR + it * 32 + xcol,
                             Ks + it * 2048 + wave * 512);
                async_copy16(Vg + (size_t)((it & 1) * 64 + srow) * 2048 + kt0 + (it >> 1) * 32 + xcol,
                             Vs + it * 2048 + wave * 512);
            }
            __syncthreads();
            // swapped QK^T: sf[nt] = S^T[key nt*16+quad*4+r][q = c]
            floatx4 sf[4];
#pragma unroll
            for (int nt = 0; nt < 4; nt++) sf[nt] = (floatx4){0.f, 0.f, 0.f, 0.f};
#pragma unroll
            for (int ks = 0; ks < 4; ks++)
#pragma unroll
                for (int nt = 0; nt < 4; nt++) {
                    bf16x8 kf = *(const bf16x8*)(Ks + ks * 2048 + (nt * 16 + c) * 32 + koff);
                    sf[nt] = __builtin_amdgcn_mfma_f32_16x16x32_bf16(kf, qf[ks], sf[nt], 0, 0, 0);
                }
            // softmax numerator, fully in-register (lane c owns q-row q0+wave*16+c)
            if (kt == qtile) {
                const int qrel = wave * 16 + c;
#pragma unroll
                for (int nt = 0; nt < 4; nt++)
#pragma unroll
                    for (int r = 0; r < 4; r++) {
                        float p = exp2f(sf[nt][r]);
                        if (nt * 16 + quad * 4 + r > qrel) p = 0.f;
                        lsum += p;
                        sf[nt][r] = p;
                    }
            } else {
#pragma unroll
                for (int nt = 0; nt < 4; nt++)
#pragma unroll
                    for (int r = 0; r < 4; r++) {
                        float p = exp2f(sf[nt][r]);
                        lsum += p;
                        sf[nt][r] = p;
                    }
            }
            // PV: pack P in-register; V key-slots sigma-matched by vtrans
#pragma unroll
            for (int kc = 0; kc < 2; kc++) {
                bf16x8 pf;
#pragma unroll
                for (int j = 0; j < 4; j++) {
                    ((bf16*)&pf)[j]     = __float2bfloat16(sf[2 * kc][j]);
                    ((bf16*)&pf)[4 + j] = __float2bfloat16(sf[2 * kc + 1][j]);
                }
#pragma unroll
                for (int nt = 0; nt < 8; nt++) {
                    bf16x8 vf = *(const bf16x8*)(Vs + kc * 4096 + (nt * 16 + c) * 32 + koff);
                    accO[nt] = __builtin_amdgcn_mfma_f32_16x16x32_bf16(pf, vf, accO[nt], 0, 0, 0);
                }
            }
            __syncthreads();
        }
        // row-sum: reduce over the 4 quads holding this q-row's keys
        {
            float v = lsum;
            v += __shfl_xor(v, 16);
            v += __shfl_xor(v, 32);
            if (quad == 0)
                Ls[(size_t)lsSlot * 65536 + ((size_t)(b * 16 + h) * 32 + qtile) * 64
                   + wave * 16 + c] = v;
        }
        const size_t orow = (size_t)b * T + q0 + wave * 16 + quad * 4;
#pragma unroll
        for (int nt = 0; nt < 8; nt++)
#pragma unroll
            for (int r = 0; r < 4; r++)
                slot[(orow + r) * 2048 + h * 128 + nt * 16 + c] =
                    __float2bfloat16(accO[nt][r]);
    };

    if (s == 0) {
        run_part(qa, 0, 17, Slot0, 0);
    } else {
        run_part(qa, 17, 32 - pj, Slot1, 1);   // empty for pj==15 -> writes zeros
        run_part(pj, 0, pj + 1, Slot0, 0);
    }
}

// ---------------- merge partials: AO = (Slot0 + Slot1) / (l0 + l1) ----------------
__global__ __launch_bounds__(256) void attn_merge(bf16* __restrict__ AO,
                                                  const bf16* __restrict__ P1,
                                                  const float* __restrict__ Ls) {
    int i = blockIdx.x * 256 + threadIdx.x;   // 1,048,576 threads, 8 cols each
    int row = i >> 8;                         // 0..4095
    int cg = (i & 255) << 3;                  // col 0..2040 step 8
    int b = row >> 11, t = row & 2047;
    int qtile = t >> 6;
    int h = cg >> 7;
    size_t off = (size_t)row * 2048 + cg;
    size_t li = ((size_t)(b * 16 + h) * 32 + qtile) * 64 + (t & 63);
    bf16x8 a0 = *(const bf16x8*)(AO + off);
    float l = Ls[li];
    float acc[8];
#pragma unroll
    for (int j = 0; j < 8; j++) acc[j] = __bfloat162float(((const bf16*)&a0)[j]);
    if (qtile >= 16) {   // q-tiles 16..31 have a second partial
        bf16x8 a1 = *(const bf16x8*)(P1 + off);
        l += Ls[65536 + li];
#pragma unroll
        for (int j = 0; j < 8; j++) acc[j] += __bfloat162float(((const bf16*)&a1)[j]);
    }
    float inv = 1.0f / l;
    bf16x8 o;
#pragma unroll
    for (int j = 0; j < 8; j++) ((bf16*)&o)[j] = __float2bfloat16(acc[j] * inv);
    *(bf16x8*)(AO + off) = o;
}

extern "C" void kernel_launch(void* const* d_in, const int* in_sizes, int n_in,
                              void* d_out, int out_size, void* d_ws, size_t ws_size,
                              hipStream_t stream) {
    const float* x  = (const float*)d_in[0];
    const float* Wq = (const float*)d_in[1];
    const float* Wk = (const float*)d_in[2];
    const float* Wv = (const float*)d_in[3];
    const float* Wo = (const float*)d_in[4];

    char* ws = (char*)d_ws;
    bf16* xb   = (bf16*)(ws);                 // [4096][2048] (dead after QKV GEMM)
    bf16* Vtg  = (bf16*)(ws);                 // reuses xb: [8][128][2048] = 4 MB
    bf16* Slt1 = (bf16*)(ws + 4194304);       // 16.78 MB, overlays dead xb-tail + Wt
    float* Ls  = (float*)(ws + 20971520);     // 0.5 MB lsum[2][b][h][qtile][64]
    bf16* Wt   = (bf16*)(ws + 16777216);      // [3072][2048] Wq|Wk|Wv (dead before flash)
    bf16* Wot  = (bf16*)(ws + 29360128);      // [2048][2048] (live until out-proj)
    bf16* QKV  = (bf16*)(ws + 37748736);      // [4096][3072]
    bf16* AO   = (bf16*)(ws + 62914560);      // [4096][2048] = partial Slot0, merged in place

    // fused prep: cast x + all weight transposes (was 5 launches)
    prep_kernel<<<18432, 256, 0, stream>>>(x, xb, Wq, Wk, Wv, Wo, Wt, Wot);

    // QKV projection: 256^2 kernel, depth-3 prefetch (R8: 63.2 us), 12x16 = 192 blocks
    gemm256<<<dim3(12, 16), 512, 0, stream>>>(xb, Wt, QKV, 4096, 3072, 2048);

    // fused RoPE(K) + V transpose (was 2 launches)
    rope_vtrans<<<6144, 256, 0, stream>>>(QKV, Vtg);

    // split-kv flash attention: 16 pairs x 2 splits x 16 heads x 2 batch = 1024 uniform blocks
    flash_attn5<<<dim3(32, 16, 2), 256, 0, stream>>>(QKV, Vtg, AO, Slt1, Ls);

    // merge partials -> AO (in place)
    attn_merge<<<4096, 256, 0, stream>>>(AO, Slt1, Ls);

    // output projection: 128x256 tiles, depth-2 (R5 config) -> grid 8x32 = 256 blocks
    gemm256g<128, 256, true><<<dim3(8, 32), 512, 0, stream>>>(AO, Wot, d_out, 4096, 2048, 2048);
}